// Round 4
// baseline (312.755 us; speedup 1.0000x reference)
//
#include <hip/hip_runtime.h>
#include <hip/hip_bf16.h>

#define N_IMG 2
#define HH 256
#define WW 256
#define HW 65536
#define PRE 1024
#define POST 256
#define NBIN 4096
#define CAPC 8192
#define NMS_THR 0.7f
#define SCORE_T 0.1f
#define MIN_SZ 4.0f

// ---------- sortable key helpers ----------
__device__ __forceinline__ unsigned int fkey(float f) {
    unsigned int u = __float_as_uint(f);
    return u ^ ((u & 0x80000000u) ? 0xFFFFFFFFu : 0x80000000u);
}
__device__ __forceinline__ float unfkey(unsigned int k) {
    unsigned int u = (k & 0x80000000u) ? (k ^ 0x80000000u) : ~k;
    return __uint_as_float(u);
}
__device__ __forceinline__ unsigned long long readlane64(unsigned long long v, int l) {
    unsigned int lo = (unsigned int)__builtin_amdgcn_readlane((int)(unsigned int)v, l);
    unsigned int hi = (unsigned int)__builtin_amdgcn_readlane((int)(unsigned int)(v >> 32), l);
    return ((unsigned long long)hi << 32) | (unsigned long long)lo;
}

// ---------- kernels ----------
__global__ void k_init(unsigned int* hist, unsigned int* ccnt) {
    int t = blockIdx.x * blockDim.x + threadIdx.x;
    if (t < N_IMG * NBIN) hist[t] = 0u;
    if (t < N_IMG) ccnt[t] = 0u;
}

__global__ void k_hist(const float* __restrict__ obj, unsigned int* hist) {
    int g = blockIdx.x * blockDim.x + threadIdx.x;   // 0 .. N_IMG*HW-1
    int img = g >> 16;
    unsigned int key = fkey(obj[g]);
    atomicAdd(&hist[img * NBIN + (key >> 20)], 1u);
}

__global__ void k_findbin(const unsigned int* __restrict__ hist, unsigned int* selB) {
    __shared__ unsigned int lh[NBIN];
    __shared__ unsigned int chunk[256];
    int img = blockIdx.x;
    int t = threadIdx.x;
    unsigned int s = 0;
    for (int k = 0; k < 16; ++k) {
        unsigned int v = hist[img * NBIN + t * 16 + k];
        lh[t * 16 + k] = v;
        s += v;
    }
    chunk[t] = s;
    __syncthreads();
    if (t == 0) {
        unsigned int run = 0;
        int c;
        for (c = 255; c >= 0; --c) {
            if (run + chunk[c] >= PRE) break;
            run += chunk[c];
        }
        unsigned int B = 0;
        for (int b = c * 16 + 15; b >= c * 16; --b) {
            if (run + lh[b] >= PRE) { B = (unsigned int)b; break; }
            run += lh[b];
        }
        selB[img] = B;
    }
}

__global__ void k_compact(const float* __restrict__ obj, const unsigned int* __restrict__ selB,
                          unsigned int* ccnt, unsigned long long* cbuf) {
    int g = blockIdx.x * blockDim.x + threadIdx.x;
    int img = g >> 16;
    int e = g & 0xFFFF;
    unsigned int key = fkey(obj[g]);
    if ((key >> 20) >= selB[img]) {
        unsigned int pos = atomicAdd(&ccnt[img], 1u);
        if (pos < CAPC) {
            cbuf[img * CAPC + pos] =
                ((unsigned long long)key << 32) | (unsigned long long)(0xFFFFFFFFu - (unsigned int)e);
        }
    }
}

__global__ __launch_bounds__(1024) void k_sort(const unsigned int* __restrict__ ccnt,
                                               const unsigned long long* __restrict__ cbuf,
                                               unsigned int* tidx, float* tscr) {
    __shared__ unsigned long long sk[CAPC];   // 64 KB
    int img = blockIdx.x;
    int t = threadIdx.x;
    unsigned int M = ccnt[img];
    if (M > CAPC) M = CAPC;
    if (M < PRE) M = PRE;          // guaranteed by k_findbin; belt-and-braces
    unsigned int NP2 = 1;
    while (NP2 < M) NP2 <<= 1;     // sort only the occupied power-of-2 prefix
    for (unsigned int i = t; i < NP2; i += 1024)
        sk[i] = (i < M) ? cbuf[img * CAPC + i] : 0ULL;
    __syncthreads();
    for (unsigned int k = 2; k <= NP2; k <<= 1) {
        for (unsigned int j = k >> 1; j > 0; j >>= 1) {
            for (unsigned int i = t; i < NP2; i += 1024) {
                unsigned int ixj = i ^ j;
                if (ixj > i) {
                    unsigned long long a = sk[i], b = sk[ixj];
                    bool up = ((i & k) == 0);
                    if (up ? (a < b) : (a > b)) { sk[i] = b; sk[ixj] = a; }
                }
            }
            __syncthreads();
        }
    }
    if (t < PRE) {
        unsigned long long v = sk[t];
        unsigned int key = (unsigned int)(v >> 32);
        unsigned int idx = 0xFFFFFFFFu - (unsigned int)(v & 0xFFFFFFFFULL);
        tidx[img * PRE + t] = idx;
        tscr[img * PRE + t] = unfkey(key);
    }
}

__global__ __launch_bounds__(1024) void k_decode(const float* __restrict__ boxreg,
                                                 const unsigned int* __restrict__ tidx,
                                                 const float* __restrict__ tscr,
                                                 float* boxes, float* corn, float* area, float* rad,
                                                 unsigned long long* vmask) {
    int img = blockIdx.x;
    int r = threadIdx.x;
    unsigned int idx = tidx[img * PRE + r];
    float sc = tscr[img * PRE + r];
    int h = (int)(idx >> 8);
    int w = (int)(idx & 255u);
    const float* rg = boxreg + (size_t)img * 5 * HW;
    float t_ = rg[0 * HW + idx] * 1024.0f;
    float rr = rg[1 * HW + idx] * 1024.0f;
    float bb = rg[2 * HW + idx] * 1024.0f;
    float ll = rg[3 * HW + idx] * 1024.0f;
    float ang = (rg[4 * HW + idx] - 0.5f) * 90.0f;
    float wd = ll + rr;
    float ht = t_ + bb;
    float xc = (float)w * 4.0f + 0.5f * (rr - ll);
    float yc = (float)h * 4.0f + 0.5f * (bb - t_);
    xc = fminf(fmaxf(xc, 0.0f), 1023.0f);
    yc = fminf(fmaxf(yc, 0.0f), 1023.0f);
    bool valid = (sc > SCORE_T) && (wd >= MIN_SZ) && (ht >= MIN_SZ);

    float* bx = boxes + (size_t)(img * PRE + r) * 5;
    bx[0] = xc; bx[1] = yc; bx[2] = wd; bx[3] = ht; bx[4] = ang;

    float th = ang * (float)(3.14159265358979323846 / 180.0);
    float c = cosf(th), s = sinf(th);
    const float dxs[4] = {-0.5f, 0.5f, 0.5f, -0.5f};
    const float dys[4] = {-0.5f, -0.5f, 0.5f, 0.5f};
    float* cr = corn + (size_t)(img * PRE + r) * 8;
#pragma unroll
    for (int k = 0; k < 4; ++k) {
        float dx = dxs[k] * wd, dy = dys[k] * ht;
        cr[2 * k]     = xc + dx * c - dy * s;
        cr[2 * k + 1] = yc + dx * s + dy * c;
    }
    area[img * PRE + r] = wd * ht;
    rad[img * PRE + r] = 0.5f * sqrtf(wd * wd + ht * ht) + 0.01f;  // tiny safety margin

    unsigned long long bal = __ballot(valid ? 1 : 0);
    if ((threadIdx.x & 63) == 0) vmask[img * 16 + (threadIdx.x >> 6)] = bal;
}

// Sutherland-Hodgman convex clip of quad A against quad B edges; mirrors reference math.
__device__ float inter_area(const float* pax, const float* pay, const float* __restrict__ cb) {
    float px[8], py[8], qx[8], qy[8];
    int n = 4;
#pragma unroll
    for (int k = 0; k < 4; ++k) { px[k] = pax[k]; py[k] = pay[k]; }
    for (int e = 0; e < 4; ++e) {
        float p1x = cb[2 * e], p1y = cb[2 * e + 1];
        int e2 = (e + 1) & 3;
        float ex = cb[2 * e2] - p1x, ey = cb[2 * e2 + 1] - p1y;
        int m = 0;
        for (int k = 0; k < n; ++k) {
            int kn = (k + 1 < n) ? k + 1 : 0;
            float dc = ex * (py[k] - p1y) - ey * (px[k] - p1x);
            float dn = ex * (py[kn] - p1y) - ey * (px[kn] - p1x);
            bool ic = dc >= 0.0f;
            bool inx = dn >= 0.0f;
            if (ic && m < 8) { qx[m] = px[k]; qy[m] = py[k]; ++m; }
            if ((ic != inx) && m < 8) {
                float den = dc - dn;
                float safe = (fabsf(den) > 1e-9f) ? den : 1.0f;
                float tt = dc / safe;
                qx[m] = px[k] + tt * (px[kn] - px[k]);
                qy[m] = py[k] + tt * (py[kn] - py[k]);
                ++m;
            }
        }
        n = m;
        for (int k = 0; k < n; ++k) { px[k] = qx[k]; py[k] = qy[k]; }
    }
    if (n < 3) return 0.0f;
    float s = 0.0f;
    for (int k = 0; k < n; ++k) {
        int kn = (k + 1 < n) ? k + 1 : 0;
        s += px[k] * py[kn] - px[kn] * py[k];
    }
    return 0.5f * fabsf(s);
}

__global__ __launch_bounds__(256) void k_iou(const float* __restrict__ boxes,
                                             const float* __restrict__ corn,
                                             const float* __restrict__ area,
                                             const float* __restrict__ rad,
                                             unsigned long long* masks) {
    int row = blockIdx.x;          // 0 .. N_IMG*PRE-1
    int img = row >> 10;
    int i = row & 1023;
    __shared__ float pax[4], pay[4], sArA, sCxA, sCyA, sRA;
    if (threadIdx.x == 0) {
        const float* cr = corn + (size_t)row * 8;
#pragma unroll
        for (int k = 0; k < 4; ++k) { pax[k] = cr[2 * k]; pay[k] = cr[2 * k + 1]; }
        sArA = area[row];
        const float* b = boxes + (size_t)row * 5;
        sCxA = b[0]; sCyA = b[1];
        sRA = rad[row];
    }
    __syncthreads();
    for (int c = 0; c < 4; ++c) {
        int j = c * 256 + threadIdx.x;
        bool flag = false;
        if (j > i) {
            int col = img * PRE + j;
            float dx = boxes[(size_t)col * 5 + 0] - sCxA;
            float dy = boxes[(size_t)col * 5 + 1] - sCyA;
            float rr = sRA + rad[col];
            if (dx * dx + dy * dy <= rr * rr) {
                const float* cbp = corn + (size_t)col * 8;
                float inter = inter_area(pax, pay, cbp);
                float uni = sArA + area[col] - inter;
                float iou = inter / fmaxf(uni, 1e-9f);
                flag = iou > NMS_THR;
            }
        }
        unsigned long long bal = __ballot(flag ? 1 : 0);
        if ((threadIdx.x & 63) == 0)
            masks[(size_t)row * 16 + c * 4 + (threadIdx.x >> 6)] = bal;
    }
}

// Blocked greedy NMS, one wave per image. Exploits: the next available (valid &
// unsuppressed) row is ALWAYS kept -> skip-scan via ffs over an SGPR avail mask
// (~5 kept rows/block instead of 64 serial iterations). Intra-block suppression
// uses a prefetched per-lane diagonal word; cross-block suppression loads only
// kept rows' mask rows, batched into 8 static slots with one deferred wait.
__global__ __launch_bounds__(64) void k_nms_out(const unsigned long long* __restrict__ masks,
                                                const unsigned long long* __restrict__ vmask,
                                                const float* __restrict__ boxes,
                                                const float* __restrict__ tscr,
                                                float* __restrict__ out) {
    int img = blockIdx.x;
    int lane = threadIdx.x;                 // 0..63, one wave
    int lw = lane & 15;                     // sup word this lane mirrors (4 copies)
    __shared__ unsigned short keptIdx[POST];
    const unsigned long long* mbase = masks + (size_t)img * PRE * 16;

    unsigned long long vmw = vmask[img * 16 + lw];   // lane w holds valid-word w
    unsigned long long supw = 0ULL;                  // lane w holds sup-word w
    // diagonal word for block 0: lane d holds mask[d][word 0]
    unsigned long long diag = mbase[(size_t)lane * 16 + 0];

    int cnt = 0;                                     // uniform (scalar) kept count
    for (int b = 0; b < 16; ++b) {
        // prefetch next block's diagonal (unconditional; b=15 reloads itself)
        int bn = (b + 1 < 16) ? b + 1 : 15;
        unsigned long long diagN = mbase[(size_t)(bn * 64 + lane) * 16 + bn];

        // avail mask for this block (uniform)
        unsigned long long avail = readlane64(vmw, b) & ~readlane64(supw, b);
        unsigned long long K = 0ULL;
        // skip-scan: next available row is always kept
        while (avail) {
            int d = __ffsll((long long)avail) - 1;
            K |= 1ULL << d;
            avail &= ~(1ULL << d);
            avail &= ~readlane64(diag, d);   // intra-block suppression by row d
        }
        // cross-block: OR kept rows' full mask rows into supw, 8 rows per pass
        unsigned long long kk = K;
        while (kk) {
            unsigned long long m0 = 0, m1 = 0, m2 = 0, m3 = 0, m4 = 0, m5 = 0, m6 = 0, m7 = 0;
#define NMS_SLOT(M)                                                              \
            if (kk) {                                                            \
                int d_ = __ffsll((long long)kk) - 1; kk &= kk - 1;               \
                int row_ = b * 64 + d_;                                          \
                M = mbase[(size_t)row_ * 16 + lw];                               \
                if (cnt < POST && lane == 0) keptIdx[cnt] = (unsigned short)row_;\
                ++cnt;                                                           \
            }
            NMS_SLOT(m0) NMS_SLOT(m1) NMS_SLOT(m2) NMS_SLOT(m3)
            NMS_SLOT(m4) NMS_SLOT(m5) NMS_SLOT(m6) NMS_SLOT(m7)
#undef NMS_SLOT
            supw |= (m0 | m1) | (m2 | m3) | ((m4 | m5) | (m6 | m7));
        }
        diag = diagN;
    }
    __syncthreads();
    int total = (cnt > POST) ? POST : cnt;
#pragma unroll
    for (int q = 0; q < POST / 64; ++q) {
        int r = q * 64 + lane;
        float v0 = 0.f, v1 = 0.f, v2 = 0.f, v3 = 0.f, v4 = 0.f, v5 = 0.f;
        if (r < total) {
            int i = keptIdx[r];
            const float* b = boxes + (size_t)(img * PRE + i) * 5;
            v0 = b[0]; v1 = b[1]; v2 = b[2]; v3 = b[3]; v4 = b[4];
            v5 = tscr[img * PRE + i];
        }
        float* o2 = out + (size_t)(img * POST + r) * 6;
        o2[0] = v0; o2[1] = v1; o2[2] = v2; o2[3] = v3; o2[4] = v4; o2[5] = v5;
    }
}

// ---------- workspace layout (all offsets 8-byte aligned) ----------
enum : size_t {
    OFF_HIST = 0,          // 2*4096*4  = 32768
    OFF_CCNT = 32768,      // 8
    OFF_SELB = 32776,      // 8
    OFF_CBUF = 32784,      // 2*8192*8  = 131072 -> 163856
    OFF_TIDX = 163856,     // 8192 -> 172048
    OFF_TSCR = 172048,     // 8192 -> 180240
    OFF_BOX  = 180240,     // 40960 -> 221200
    OFF_CORN = 221200,     // 65536 -> 286736
    OFF_AREA = 286736,     // 8192 -> 294928
    OFF_RAD  = 294928,     // 8192 -> 303120
    OFF_VMSK = 303120,     // 256 -> 303376
    OFF_MASK = 303376,     // 262144 -> 565520
};

extern "C" void kernel_launch(void* const* d_in, const int* in_sizes, int n_in,
                              void* d_out, int out_size, void* d_ws, size_t ws_size,
                              hipStream_t stream) {
    const float* obj = (const float*)d_in[0];       // (2,1,256,256) f32
    const float* boxreg = (const float*)d_in[1];    // (2,5,256,256) f32
    float* out = (float*)d_out;                     // (2,256,6) f32

    char* w = (char*)d_ws;
    unsigned int* hist = (unsigned int*)(w + OFF_HIST);
    unsigned int* ccnt = (unsigned int*)(w + OFF_CCNT);
    unsigned int* selB = (unsigned int*)(w + OFF_SELB);
    unsigned long long* cbuf = (unsigned long long*)(w + OFF_CBUF);
    unsigned int* tidx = (unsigned int*)(w + OFF_TIDX);
    float* tscr = (float*)(w + OFF_TSCR);
    float* boxes = (float*)(w + OFF_BOX);
    float* corn = (float*)(w + OFF_CORN);
    float* area = (float*)(w + OFF_AREA);
    float* rad = (float*)(w + OFF_RAD);
    unsigned long long* vmask = (unsigned long long*)(w + OFF_VMSK);
    unsigned long long* masks = (unsigned long long*)(w + OFF_MASK);

    k_init<<<32, 256, 0, stream>>>(hist, ccnt);
    k_hist<<<(N_IMG * HW) / 256, 256, 0, stream>>>(obj, hist);
    k_findbin<<<N_IMG, 256, 0, stream>>>(hist, selB);
    k_compact<<<(N_IMG * HW) / 256, 256, 0, stream>>>(obj, selB, ccnt, cbuf);
    k_sort<<<N_IMG, 1024, 0, stream>>>(ccnt, cbuf, tidx, tscr);
    k_decode<<<N_IMG, 1024, 0, stream>>>(boxreg, tidx, tscr, boxes, corn, area, rad, vmask);
    k_iou<<<N_IMG * PRE, 256, 0, stream>>>(boxes, corn, area, rad, masks);
    k_nms_out<<<N_IMG, 64, 0, stream>>>(masks, vmask, boxes, tscr, out);
}

// Round 6
// 202.524 us; speedup vs baseline: 1.5443x; 1.5443x over previous
//
#include <hip/hip_runtime.h>
#include <hip/hip_bf16.h>

#define N_IMG 2
#define HH 256
#define WW 256
#define HW 65536
#define PRE 1024
#define POST 256
#define NBIN 4096
#define SORTN 4096
#define NMS_THR 0.7f
#define SCORE_T 0.1f
#define MIN_SZ 4.0f

// ---------- sortable key helpers ----------
__device__ __forceinline__ unsigned int fkey(float f) {
    unsigned int u = __float_as_uint(f);
    return u ^ ((u & 0x80000000u) ? 0xFFFFFFFFu : 0x80000000u);
}
__device__ __forceinline__ float unfkey(unsigned int k) {
    unsigned int u = (k & 0x80000000u) ? (k ^ 0x80000000u) : ~k;
    return __uint_as_float(u);
}
__device__ __forceinline__ unsigned long long readlane64(unsigned long long v, int l) {
    unsigned int lo = (unsigned int)__builtin_amdgcn_readlane((int)(unsigned int)v, l);
    unsigned int hi = (unsigned int)__builtin_amdgcn_readlane((int)(unsigned int)(v >> 32), l);
    return ((unsigned long long)hi << 32) | (unsigned long long)lo;
}

// ============================================================================
// K1: fused top-k selection (hist -> bin -> compact -> bitonic sort) + decode.
// One workgroup per image; all intermediate state lives in LDS.
// ============================================================================
__global__ __launch_bounds__(1024) void k_select(const float* __restrict__ obj,
                                                 const float* __restrict__ boxreg,
                                                 float* boxes, float* corn, float* area, float* rad,
                                                 unsigned long long* vmask, float* tscr) {
    __shared__ unsigned int hist[NBIN];          // 16 KB
    __shared__ unsigned int c16[256];
    __shared__ unsigned int sB;
    __shared__ unsigned int scount;
    __shared__ unsigned long long sk[SORTN];     // 32 KB
    int img = blockIdx.x;
    int t = threadIdx.x;
    const float* o = obj + (size_t)img * HW;

    // A: zero
    for (int i = t; i < NBIN; i += 1024) hist[i] = 0u;
    if (t == 0) scount = 0u;
    __syncthreads();

    // B: 12-bit-prefix histogram, float4 loads (64 scores/thread)
    const float4* o4 = (const float4*)o;
    for (int k = 0; k < 16; ++k) {
        float4 v = o4[t + k * 1024];
        atomicAdd(&hist[fkey(v.x) >> 20], 1u);
        atomicAdd(&hist[fkey(v.y) >> 20], 1u);
        atomicAdd(&hist[fkey(v.z) >> 20], 1u);
        atomicAdd(&hist[fkey(v.w) >> 20], 1u);
    }
    __syncthreads();

    // C: find threshold bin B (count of bins > B is < PRE <= count of bins >= B)
    if (t < 256) {
        unsigned int s = 0;
        for (int k = 0; k < 16; ++k) s += hist[t * 16 + k];
        c16[t] = s;
    }
    __syncthreads();
    if (t < 64) {                                 // wave 0
        unsigned int g = c16[4 * t] + c16[4 * t + 1] + c16[4 * t + 2] + c16[4 * t + 3];
        unsigned int s = g;                       // inclusive suffix sum over lanes
        for (int d = 1; d < 64; d <<= 1) {
            unsigned int ov = __shfl_down(s, d, 64);
            if (t + d < 64) s += ov;
        }
        unsigned int sexcl = s - g;
        if (sexcl < PRE && s >= PRE) {            // exactly one lane
            unsigned int run = sexcl;
            int chunk = 4 * t;
            for (int q = 3; q >= 0; --q) {
                unsigned int cv = c16[4 * t + q];
                if (run + cv >= PRE) { chunk = 4 * t + q; break; }
                run += cv;
            }
            unsigned int B = 0;
            for (int b = chunk * 16 + 15; b >= chunk * 16; --b) {
                unsigned int hv = hist[b];
                if (run + hv >= PRE) { B = (unsigned int)b; break; }
                run += hv;
            }
            sB = B;
        }
    }
    __syncthreads();
    unsigned int B = sB;

    // D: compact candidates into LDS. float4 loads so ALL 65536 elements are
    // covered (R4 bug: scalar loop only scanned 16384 -> garbage ranks -> OOB).
    for (int k = 0; k < 16; ++k) {
        int j4 = t + k * 1024;                    // float4 index
        float4 v = o4[j4];
        float vs[4] = {v.x, v.y, v.z, v.w};
#pragma unroll
        for (int c = 0; c < 4; ++c) {
            unsigned int key = fkey(vs[c]);
            if ((key >> 20) >= B) {
                unsigned int i = (unsigned int)(4 * j4 + c);
                unsigned int pos = atomicAdd(&scount, 1u);
                if (pos < SORTN)
                    sk[pos] = ((unsigned long long)key << 32) |
                              (unsigned long long)(0xFFFFFFFFu - i);
            }
        }
    }
    __syncthreads();
    unsigned int M = scount; if (M > SORTN) M = SORTN;
    unsigned int NP2 = 1; while (NP2 < M) NP2 <<= 1;
    if (NP2 < PRE) NP2 = PRE;
    for (unsigned int i = M + t; i < NP2; i += 1024) sk[i] = 0ULL;
    __syncthreads();

    // E: bitonic sort (descending), NP2 <= 4096
    for (unsigned int k2 = 2; k2 <= NP2; k2 <<= 1) {
        for (unsigned int j = k2 >> 1; j > 0; j >>= 1) {
            for (unsigned int i = t; i < NP2; i += 1024) {
                unsigned int ixj = i ^ j;
                if (ixj > i) {
                    unsigned long long a = sk[i], b = sk[ixj];
                    bool up = ((i & k2) == 0);
                    if (up ? (a < b) : (a > b)) { sk[i] = b; sk[ixj] = a; }
                }
            }
            __syncthreads();
        }
    }

    // F: decode top-1024 (thread t owns rank t)
    {
        unsigned long long v = sk[t];
        unsigned int key = (unsigned int)(v >> 32);
        unsigned int idx = (0xFFFFFFFFu - (unsigned int)(v & 0xFFFFFFFFULL)) & 0xFFFFu; // in-bounds always
        float sc = unfkey(key);
        int h = (int)(idx >> 8);
        int w = (int)(idx & 255u);
        const float* rg = boxreg + (size_t)img * 5 * HW;
        float t_ = rg[0 * HW + idx] * 1024.0f;
        float rr = rg[1 * HW + idx] * 1024.0f;
        float bb = rg[2 * HW + idx] * 1024.0f;
        float ll = rg[3 * HW + idx] * 1024.0f;
        float ang = (rg[4 * HW + idx] - 0.5f) * 90.0f;
        float wd = ll + rr;
        float ht = t_ + bb;
        float xc = (float)w * 4.0f + 0.5f * (rr - ll);
        float yc = (float)h * 4.0f + 0.5f * (bb - t_);
        xc = fminf(fmaxf(xc, 0.0f), 1023.0f);
        yc = fminf(fmaxf(yc, 0.0f), 1023.0f);
        bool valid = (sc > SCORE_T) && (wd >= MIN_SZ) && (ht >= MIN_SZ);

        float* bx = boxes + (size_t)(img * PRE + t) * 5;
        bx[0] = xc; bx[1] = yc; bx[2] = wd; bx[3] = ht; bx[4] = ang;
        tscr[img * PRE + t] = sc;

        float th = ang * (float)(3.14159265358979323846 / 180.0);
        float c = cosf(th), s = sinf(th);
        const float dxs[4] = {-0.5f, 0.5f, 0.5f, -0.5f};
        const float dys[4] = {-0.5f, -0.5f, 0.5f, 0.5f};
        float* cr = corn + (size_t)(img * PRE + t) * 8;
#pragma unroll
        for (int k = 0; k < 4; ++k) {
            float dx = dxs[k] * wd, dy = dys[k] * ht;
            cr[2 * k]     = xc + dx * c - dy * s;
            cr[2 * k + 1] = yc + dx * s + dy * c;
        }
        area[img * PRE + t] = wd * ht;
        rad[img * PRE + t] = 0.5f * sqrtf(wd * wd + ht * ht) + 0.01f;

        unsigned long long bal = __ballot(valid ? 1 : 0);
        if ((t & 63) == 0) vmask[img * 16 + (t >> 6)] = bal;
    }
}

// ============================================================================
// K2: rotated-IoU suppression masks (unchanged this round)
// ============================================================================
__device__ float inter_area(const float* pax, const float* pay, const float* __restrict__ cb) {
    float px[8], py[8], qx[8], qy[8];
    int n = 4;
#pragma unroll
    for (int k = 0; k < 4; ++k) { px[k] = pax[k]; py[k] = pay[k]; }
    for (int e = 0; e < 4; ++e) {
        float p1x = cb[2 * e], p1y = cb[2 * e + 1];
        int e2 = (e + 1) & 3;
        float ex = cb[2 * e2] - p1x, ey = cb[2 * e2 + 1] - p1y;
        int m = 0;
        for (int k = 0; k < n; ++k) {
            int kn = (k + 1 < n) ? k + 1 : 0;
            float dc = ex * (py[k] - p1y) - ey * (px[k] - p1x);
            float dn = ex * (py[kn] - p1y) - ey * (px[kn] - p1x);
            bool ic = dc >= 0.0f;
            bool inx = dn >= 0.0f;
            if (ic && m < 8) { qx[m] = px[k]; qy[m] = py[k]; ++m; }
            if ((ic != inx) && m < 8) {
                float den = dc - dn;
                float safe = (fabsf(den) > 1e-9f) ? den : 1.0f;
                float tt = dc / safe;
                qx[m] = px[k] + tt * (px[kn] - px[k]);
                qy[m] = py[k] + tt * (py[kn] - py[k]);
                ++m;
            }
        }
        n = m;
        for (int k = 0; k < n; ++k) { px[k] = qx[k]; py[k] = qy[k]; }
    }
    if (n < 3) return 0.0f;
    float s = 0.0f;
    for (int k = 0; k < n; ++k) {
        int kn = (k + 1 < n) ? k + 1 : 0;
        s += px[k] * py[kn] - px[kn] * py[k];
    }
    return 0.5f * fabsf(s);
}

__global__ __launch_bounds__(256) void k_iou(const float* __restrict__ boxes,
                                             const float* __restrict__ corn,
                                             const float* __restrict__ area,
                                             const float* __restrict__ rad,
                                             unsigned long long* masks) {
    int row = blockIdx.x;          // 0 .. N_IMG*PRE-1
    int img = row >> 10;
    int i = row & 1023;
    __shared__ float pax[4], pay[4], sArA, sCxA, sCyA, sRA;
    if (threadIdx.x == 0) {
        const float* cr = corn + (size_t)row * 8;
#pragma unroll
        for (int k = 0; k < 4; ++k) { pax[k] = cr[2 * k]; pay[k] = cr[2 * k + 1]; }
        sArA = area[row];
        const float* b = boxes + (size_t)row * 5;
        sCxA = b[0]; sCyA = b[1];
        sRA = rad[row];
    }
    __syncthreads();
    for (int c = 0; c < 4; ++c) {
        int j = c * 256 + threadIdx.x;
        bool flag = false;
        if (j > i) {
            int col = img * PRE + j;
            float dx = boxes[(size_t)col * 5 + 0] - sCxA;
            float dy = boxes[(size_t)col * 5 + 1] - sCyA;
            float rr = sRA + rad[col];
            if (dx * dx + dy * dy <= rr * rr) {
                const float* cbp = corn + (size_t)col * 8;
                float inter = inter_area(pax, pay, cbp);
                float uni = sArA + area[col] - inter;
                float iou = inter / fmaxf(uni, 1e-9f);
                flag = iou > NMS_THR;
            }
        }
        unsigned long long bal = __ballot(flag ? 1 : 0);
        if ((threadIdx.x & 63) == 0)
            masks[(size_t)row * 16 + c * 4 + (threadIdx.x >> 6)] = bal;
    }
}

// ============================================================================
// K3: greedy NMS with the ENTIRE mask matrix staged in LDS (128 KB), then a
// single-wave skip-scan (next available row is always kept) whose critical
// chain is one ds_read per kept row. Fused output emission.
// ============================================================================
__global__ __launch_bounds__(1024) void k_nms_out(const unsigned long long* __restrict__ masks,
                                                  const unsigned long long* __restrict__ vmask,
                                                  const float* __restrict__ boxes,
                                                  const float* __restrict__ tscr,
                                                  float* __restrict__ out) {
    __shared__ unsigned long long lm[PRE * 16];   // 128 KB: lm[row*16 + word]
    __shared__ unsigned short keptIdx[POST];
    __shared__ int sTotal;
    int img = blockIdx.x;
    int t = threadIdx.x;
    const unsigned long long* mbase = masks + (size_t)img * PRE * 16;

    // cooperative stage: 16384 words via 16B loads
    {
        const ulonglong2* src = (const ulonglong2*)mbase;
        ulonglong2* dst = (ulonglong2*)lm;
#pragma unroll
        for (int k = 0; k < 8; ++k) dst[t + k * 1024] = src[t + k * 1024];
    }
    __syncthreads();

    if (t < 64) {                                 // wave 0 does the serial scan
        int lane = t;
        int lw = lane & 15;                       // word mirrored x4 across lanes
        unsigned long long vmw = vmask[img * 16 + lw];
        unsigned long long supw = 0ULL;
        int cnt = 0;
        for (int b = 0; b < 16; ++b) {
            unsigned long long avail = readlane64(vmw, b) & ~readlane64(supw, b);
            while (avail) {                       // next available row is always kept
                int d = __ffsll((long long)avail) - 1;
                avail &= avail - 1;
                int row = b * 64 + d;
                unsigned long long rw = lm[row * 16 + lw];   // LDS: the chain link
                supw |= rw;
                avail &= ~readlane64(rw, b);
                if (lane == 0 && cnt < POST) keptIdx[cnt] = (unsigned short)row;
                ++cnt;
            }
        }
        if (lane == 0) sTotal = (cnt > POST) ? POST : cnt;
    }
    __syncthreads();

    int total = sTotal;
    if (t < POST) {
        float v0 = 0.f, v1 = 0.f, v2 = 0.f, v3 = 0.f, v4 = 0.f, v5 = 0.f;
        if (t < total) {
            int i = keptIdx[t];
            const float* b = boxes + (size_t)(img * PRE + i) * 5;
            v0 = b[0]; v1 = b[1]; v2 = b[2]; v3 = b[3]; v4 = b[4];
            v5 = tscr[img * PRE + i];
        }
        float* o2 = out + (size_t)(img * POST + t) * 6;
        o2[0] = v0; o2[1] = v1; o2[2] = v2; o2[3] = v3; o2[4] = v4; o2[5] = v5;
    }
}

// ---------- workspace layout (all offsets 16-byte aligned) ----------
enum : size_t {
    OFF_BOX  = 0,          // 2*1024*5*4 = 40960
    OFF_CORN = 40960,      // 2*1024*8*4 = 65536 -> 106496
    OFF_AREA = 106496,     // 8192 -> 114688
    OFF_RAD  = 114688,     // 8192 -> 122880
    OFF_VMSK = 122880,     // 256  -> 123136
    OFF_TSCR = 123136,     // 8192 -> 131328
    OFF_MASK = 131328,     // 2*1024*16*8 = 262144 -> 393472
};

extern "C" void kernel_launch(void* const* d_in, const int* in_sizes, int n_in,
                              void* d_out, int out_size, void* d_ws, size_t ws_size,
                              hipStream_t stream) {
    const float* obj = (const float*)d_in[0];       // (2,1,256,256) f32
    const float* boxreg = (const float*)d_in[1];    // (2,5,256,256) f32
    float* out = (float*)d_out;                     // (2,256,6) f32

    char* w = (char*)d_ws;
    float* boxes = (float*)(w + OFF_BOX);
    float* corn = (float*)(w + OFF_CORN);
    float* area = (float*)(w + OFF_AREA);
    float* rad = (float*)(w + OFF_RAD);
    unsigned long long* vmask = (unsigned long long*)(w + OFF_VMSK);
    float* tscr = (float*)(w + OFF_TSCR);
    unsigned long long* masks = (unsigned long long*)(w + OFF_MASK);

    k_select<<<N_IMG, 1024, 0, stream>>>(obj, boxreg, boxes, corn, area, rad, vmask, tscr);
    k_iou<<<N_IMG * PRE, 256, 0, stream>>>(boxes, corn, area, rad, masks);
    k_nms_out<<<N_IMG, 1024, 0, stream>>>(masks, vmask, boxes, tscr, out);
}

// Round 7
// 142.383 us; speedup vs baseline: 2.1966x; 1.4224x over previous
//
#include <hip/hip_runtime.h>
#include <hip/hip_bf16.h>

#define N_IMG 2
#define HH 256
#define WW 256
#define HW 65536
#define PRE 1024
#define POST 256
#define NBIN 4096
#define SORTN 4096
#define NMS_THR 0.7f
#define SCORE_T 0.1f
#define MIN_SZ 4.0f

// ---------- sortable key helpers ----------
__device__ __forceinline__ unsigned int fkey(float f) {
    unsigned int u = __float_as_uint(f);
    return u ^ ((u & 0x80000000u) ? 0xFFFFFFFFu : 0x80000000u);
}
__device__ __forceinline__ float unfkey(unsigned int k) {
    unsigned int u = (k & 0x80000000u) ? (k ^ 0x80000000u) : ~k;
    return __uint_as_float(u);
}
__device__ __forceinline__ unsigned long long readlane64(unsigned long long v, int l) {
    unsigned int lo = (unsigned int)__builtin_amdgcn_readlane((int)(unsigned int)v, l);
    unsigned int hi = (unsigned int)__builtin_amdgcn_readlane((int)(unsigned int)(v >> 32), l);
    return ((unsigned long long)hi << 32) | (unsigned long long)lo;
}

// ============================================================================
// K1: fused top-k selection (hist -> bin -> compact -> bitonic sort) + decode.
// One workgroup per image; all intermediate state lives in LDS.
// ============================================================================
__global__ __launch_bounds__(1024) void k_select(const float* __restrict__ obj,
                                                 const float* __restrict__ boxreg,
                                                 float* boxes, float* corn, float* area, float* rad,
                                                 unsigned long long* vmask, float* tscr) {
    __shared__ unsigned int hist[NBIN];          // 16 KB
    __shared__ unsigned int c16[256];
    __shared__ unsigned int sB;
    __shared__ unsigned int scount;
    __shared__ unsigned long long sk[SORTN];     // 32 KB
    int img = blockIdx.x;
    int t = threadIdx.x;
    const float* o = obj + (size_t)img * HW;

    // A: zero
    for (int i = t; i < NBIN; i += 1024) hist[i] = 0u;
    if (t == 0) scount = 0u;
    __syncthreads();

    // B: 12-bit-prefix histogram, float4 loads (64 scores/thread)
    const float4* o4 = (const float4*)o;
    for (int k = 0; k < 16; ++k) {
        float4 v = o4[t + k * 1024];
        atomicAdd(&hist[fkey(v.x) >> 20], 1u);
        atomicAdd(&hist[fkey(v.y) >> 20], 1u);
        atomicAdd(&hist[fkey(v.z) >> 20], 1u);
        atomicAdd(&hist[fkey(v.w) >> 20], 1u);
    }
    __syncthreads();

    // C: find threshold bin B (count of bins > B is < PRE <= count of bins >= B)
    if (t < 256) {
        unsigned int s = 0;
        for (int k = 0; k < 16; ++k) s += hist[t * 16 + k];
        c16[t] = s;
    }
    __syncthreads();
    if (t < 64) {                                 // wave 0
        unsigned int g = c16[4 * t] + c16[4 * t + 1] + c16[4 * t + 2] + c16[4 * t + 3];
        unsigned int s = g;                       // inclusive suffix sum over lanes
        for (int d = 1; d < 64; d <<= 1) {
            unsigned int ov = __shfl_down(s, d, 64);
            if (t + d < 64) s += ov;
        }
        unsigned int sexcl = s - g;
        if (sexcl < PRE && s >= PRE) {            // exactly one lane
            unsigned int run = sexcl;
            int chunk = 4 * t;
            for (int q = 3; q >= 0; --q) {
                unsigned int cv = c16[4 * t + q];
                if (run + cv >= PRE) { chunk = 4 * t + q; break; }
                run += cv;
            }
            unsigned int B = 0;
            for (int b = chunk * 16 + 15; b >= chunk * 16; --b) {
                unsigned int hv = hist[b];
                if (run + hv >= PRE) { B = (unsigned int)b; break; }
                run += hv;
            }
            sB = B;
        }
    }
    __syncthreads();
    unsigned int B = sB;

    // D: compact candidates into LDS; float4 loads cover ALL 65536 elements.
    for (int k = 0; k < 16; ++k) {
        int j4 = t + k * 1024;                    // float4 index
        float4 v = o4[j4];
        float vs[4] = {v.x, v.y, v.z, v.w};
#pragma unroll
        for (int c = 0; c < 4; ++c) {
            unsigned int key = fkey(vs[c]);
            if ((key >> 20) >= B) {
                unsigned int i = (unsigned int)(4 * j4 + c);
                unsigned int pos = atomicAdd(&scount, 1u);
                if (pos < SORTN)
                    sk[pos] = ((unsigned long long)key << 32) |
                              (unsigned long long)(0xFFFFFFFFu - i);
            }
        }
    }
    __syncthreads();
    unsigned int M = scount; if (M > SORTN) M = SORTN;
    unsigned int NP2 = 1; while (NP2 < M) NP2 <<= 1;
    if (NP2 < PRE) NP2 = PRE;
    for (unsigned int i = M + t; i < NP2; i += 1024) sk[i] = 0ULL;
    __syncthreads();

    // E: bitonic sort (descending), NP2 <= 4096
    for (unsigned int k2 = 2; k2 <= NP2; k2 <<= 1) {
        for (unsigned int j = k2 >> 1; j > 0; j >>= 1) {
            for (unsigned int i = t; i < NP2; i += 1024) {
                unsigned int ixj = i ^ j;
                if (ixj > i) {
                    unsigned long long a = sk[i], b = sk[ixj];
                    bool up = ((i & k2) == 0);
                    if (up ? (a < b) : (a > b)) { sk[i] = b; sk[ixj] = a; }
                }
            }
            __syncthreads();
        }
    }

    // F: decode top-1024 (thread t owns rank t)
    {
        unsigned long long v = sk[t];
        unsigned int key = (unsigned int)(v >> 32);
        unsigned int idx = (0xFFFFFFFFu - (unsigned int)(v & 0xFFFFFFFFULL)) & 0xFFFFu; // in-bounds always
        float sc = unfkey(key);
        int h = (int)(idx >> 8);
        int w = (int)(idx & 255u);
        const float* rg = boxreg + (size_t)img * 5 * HW;
        float t_ = rg[0 * HW + idx] * 1024.0f;
        float rr = rg[1 * HW + idx] * 1024.0f;
        float bb = rg[2 * HW + idx] * 1024.0f;
        float ll = rg[3 * HW + idx] * 1024.0f;
        float ang = (rg[4 * HW + idx] - 0.5f) * 90.0f;
        float wd = ll + rr;
        float ht = t_ + bb;
        float xc = (float)w * 4.0f + 0.5f * (rr - ll);
        float yc = (float)h * 4.0f + 0.5f * (bb - t_);
        xc = fminf(fmaxf(xc, 0.0f), 1023.0f);
        yc = fminf(fmaxf(yc, 0.0f), 1023.0f);
        bool valid = (sc > SCORE_T) && (wd >= MIN_SZ) && (ht >= MIN_SZ);

        float* bx = boxes + (size_t)(img * PRE + t) * 5;
        bx[0] = xc; bx[1] = yc; bx[2] = wd; bx[3] = ht; bx[4] = ang;
        tscr[img * PRE + t] = sc;

        float th = ang * (float)(3.14159265358979323846 / 180.0);
        float c = cosf(th), s = sinf(th);
        const float dxs[4] = {-0.5f, 0.5f, 0.5f, -0.5f};
        const float dys[4] = {-0.5f, -0.5f, 0.5f, 0.5f};
        float* cr = corn + (size_t)(img * PRE + t) * 8;
#pragma unroll
        for (int k = 0; k < 4; ++k) {
            float dx = dxs[k] * wd, dy = dys[k] * ht;
            cr[2 * k]     = xc + dx * c - dy * s;
            cr[2 * k + 1] = yc + dx * s + dy * c;
        }
        area[img * PRE + t] = wd * ht;
        rad[img * PRE + t] = 0.5f * sqrtf(wd * wd + ht * ht) + 0.01f;

        unsigned long long bal = __ballot(valid ? 1 : 0);
        if ((t & 63) == 0) vmask[img * 16 + (t >> 6)] = bal;
    }
}

// ============================================================================
// K2: rotated-IoU suppression masks (unchanged this round)
// ============================================================================
__device__ float inter_area(const float* pax, const float* pay, const float* __restrict__ cb) {
    float px[8], py[8], qx[8], qy[8];
    int n = 4;
#pragma unroll
    for (int k = 0; k < 4; ++k) { px[k] = pax[k]; py[k] = pay[k]; }
    for (int e = 0; e < 4; ++e) {
        float p1x = cb[2 * e], p1y = cb[2 * e + 1];
        int e2 = (e + 1) & 3;
        float ex = cb[2 * e2] - p1x, ey = cb[2 * e2 + 1] - p1y;
        int m = 0;
        for (int k = 0; k < n; ++k) {
            int kn = (k + 1 < n) ? k + 1 : 0;
            float dc = ex * (py[k] - p1y) - ey * (px[k] - p1x);
            float dn = ex * (py[kn] - p1y) - ey * (px[kn] - p1x);
            bool ic = dc >= 0.0f;
            bool inx = dn >= 0.0f;
            if (ic && m < 8) { qx[m] = px[k]; qy[m] = py[k]; ++m; }
            if ((ic != inx) && m < 8) {
                float den = dc - dn;
                float safe = (fabsf(den) > 1e-9f) ? den : 1.0f;
                float tt = dc / safe;
                qx[m] = px[k] + tt * (px[kn] - px[k]);
                qy[m] = py[k] + tt * (py[kn] - py[k]);
                ++m;
            }
        }
        n = m;
        for (int k = 0; k < n; ++k) { px[k] = qx[k]; py[k] = qy[k]; }
    }
    if (n < 3) return 0.0f;
    float s = 0.0f;
    for (int k = 0; k < n; ++k) {
        int kn = (k + 1 < n) ? k + 1 : 0;
        s += px[k] * py[kn] - px[kn] * py[k];
    }
    return 0.5f * fabsf(s);
}

__global__ __launch_bounds__(256) void k_iou(const float* __restrict__ boxes,
                                             const float* __restrict__ corn,
                                             const float* __restrict__ area,
                                             const float* __restrict__ rad,
                                             unsigned long long* masks) {
    int row = blockIdx.x;          // 0 .. N_IMG*PRE-1
    int img = row >> 10;
    int i = row & 1023;
    __shared__ float pax[4], pay[4], sArA, sCxA, sCyA, sRA;
    if (threadIdx.x == 0) {
        const float* cr = corn + (size_t)row * 8;
#pragma unroll
        for (int k = 0; k < 4; ++k) { pax[k] = cr[2 * k]; pay[k] = cr[2 * k + 1]; }
        sArA = area[row];
        const float* b = boxes + (size_t)row * 5;
        sCxA = b[0]; sCyA = b[1];
        sRA = rad[row];
    }
    __syncthreads();
    for (int c = 0; c < 4; ++c) {
        int j = c * 256 + threadIdx.x;
        bool flag = false;
        if (j > i) {
            int col = img * PRE + j;
            float dx = boxes[(size_t)col * 5 + 0] - sCxA;
            float dy = boxes[(size_t)col * 5 + 1] - sCyA;
            float rr = sRA + rad[col];
            if (dx * dx + dy * dy <= rr * rr) {
                const float* cbp = corn + (size_t)col * 8;
                float inter = inter_area(pax, pay, cbp);
                float uni = sArA + area[col] - inter;
                float iou = inter / fmaxf(uni, 1e-9f);
                flag = iou > NMS_THR;
            }
        }
        unsigned long long bal = __ballot(flag ? 1 : 0);
        if ((threadIdx.x & 63) == 0)
            masks[(size_t)row * 16 + c * 4 + (threadIdx.x >> 6)] = bal;
    }
}

// ============================================================================
// K3: greedy NMS, mask matrix in LDS. Early-stop at POST kept rows (output
// needs only the first 256 kept) + batch-4 speculative ds_reads so the serial
// chain pays one LDS latency per 4 rows instead of per row.
// ============================================================================
__global__ __launch_bounds__(1024) void k_nms_out(const unsigned long long* __restrict__ masks,
                                                  const unsigned long long* __restrict__ vmask,
                                                  const float* __restrict__ boxes,
                                                  const float* __restrict__ tscr,
                                                  float* __restrict__ out) {
    __shared__ unsigned long long lm[PRE * 16];   // 128 KB: lm[row*16 + word]
    __shared__ unsigned short keptIdx[POST];
    __shared__ int sTotal;
    int img = blockIdx.x;
    int t = threadIdx.x;
    const unsigned long long* mbase = masks + (size_t)img * PRE * 16;

    // cooperative stage: 16384 words via 16B loads
    {
        const ulonglong2* src = (const ulonglong2*)mbase;
        ulonglong2* dst = (ulonglong2*)lm;
#pragma unroll
        for (int k = 0; k < 8; ++k) dst[t + k * 1024] = src[t + k * 1024];
    }
    __syncthreads();

    if (t < 64) {                                 // wave 0 does the serial scan
        int lane = t;
        int lw = lane & 15;                       // word mirrored x4 across lanes
        unsigned long long vmw = vmask[img * 16 + lw];
        unsigned long long supw = 0ULL;
        int cnt = 0;
        for (int b = 0; b < 16 && cnt < POST; ++b) {
            unsigned long long avail = readlane64(vmw, b) & ~readlane64(supw, b);
            while (avail && cnt < POST) {
                // extract up to 4 lowest candidate bits (SALU)
                unsigned long long a = avail;
                int d0 = __ffsll((long long)a) - 1; a &= a - 1;
                int d1 = a ? __ffsll((long long)a) - 1 : 64; a &= a - 1;
                int d2 = a ? __ffsll((long long)a) - 1 : 64; a &= a - 1;
                int d3 = a ? __ffsll((long long)a) - 1 : 64; a &= a - 1;
                int r0 = b * 64 + d0;
                int r1 = b * 64 + (d1 & 63);
                int r2 = b * 64 + (d2 & 63);
                int r3 = b * 64 + (d3 & 63);
                // speculative parallel LDS reads: one latency covers all four
                unsigned long long w0 = lm[r0 * 16 + lw];
                unsigned long long w1 = lm[r1 * 16 + lw];
                unsigned long long w2 = lm[r2 * 16 + lw];
                unsigned long long w3 = lm[r3 * 16 + lw];
                // greedy resolution within the batch (all branches wave-uniform)
                unsigned long long sb = readlane64(w0, b);   // row r0 always kept
                supw |= w0;
                if (lane == 0) keptIdx[cnt] = (unsigned short)r0;
                ++cnt;
                if (d1 < 64 && cnt < POST && !((sb >> d1) & 1ULL)) {
                    sb |= readlane64(w1, b);
                    supw |= w1;
                    if (lane == 0) keptIdx[cnt] = (unsigned short)r1;
                    ++cnt;
                }
                if (d2 < 64 && cnt < POST && !((sb >> d2) & 1ULL)) {
                    sb |= readlane64(w2, b);
                    supw |= w2;
                    if (lane == 0) keptIdx[cnt] = (unsigned short)r2;
                    ++cnt;
                }
                if (d3 < 64 && cnt < POST && !((sb >> d3) & 1ULL)) {
                    sb |= readlane64(w3, b);
                    supw |= w3;
                    if (lane == 0) keptIdx[cnt] = (unsigned short)r3;
                    ++cnt;
                }
                avail = a & ~sb;
            }
        }
        if (lane == 0) sTotal = cnt;
    }
    __syncthreads();

    int total = sTotal;
    if (t < POST) {
        float v0 = 0.f, v1 = 0.f, v2 = 0.f, v3 = 0.f, v4 = 0.f, v5 = 0.f;
        if (t < total) {
            int i = keptIdx[t];
            const float* b = boxes + (size_t)(img * PRE + i) * 5;
            v0 = b[0]; v1 = b[1]; v2 = b[2]; v3 = b[3]; v4 = b[4];
            v5 = tscr[img * PRE + i];
        }
        float* o2 = out + (size_t)(img * POST + t) * 6;
        o2[0] = v0; o2[1] = v1; o2[2] = v2; o2[3] = v3; o2[4] = v4; o2[5] = v5;
    }
}

// ---------- workspace layout (all offsets 16-byte aligned) ----------
enum : size_t {
    OFF_BOX  = 0,          // 2*1024*5*4 = 40960
    OFF_CORN = 40960,      // 2*1024*8*4 = 65536 -> 106496
    OFF_AREA = 106496,     // 8192 -> 114688
    OFF_RAD  = 114688,     // 8192 -> 122880
    OFF_VMSK = 122880,     // 256  -> 123136
    OFF_TSCR = 123136,     // 8192 -> 131328
    OFF_MASK = 131328,     // 2*1024*16*8 = 262144 -> 393472
};

extern "C" void kernel_launch(void* const* d_in, const int* in_sizes, int n_in,
                              void* d_out, int out_size, void* d_ws, size_t ws_size,
                              hipStream_t stream) {
    const float* obj = (const float*)d_in[0];       // (2,1,256,256) f32
    const float* boxreg = (const float*)d_in[1];    // (2,5,256,256) f32
    float* out = (float*)d_out;                     // (2,256,6) f32

    char* w = (char*)d_ws;
    float* boxes = (float*)(w + OFF_BOX);
    float* corn = (float*)(w + OFF_CORN);
    float* area = (float*)(w + OFF_AREA);
    float* rad = (float*)(w + OFF_RAD);
    unsigned long long* vmask = (unsigned long long*)(w + OFF_VMSK);
    float* tscr = (float*)(w + OFF_TSCR);
    unsigned long long* masks = (unsigned long long*)(w + OFF_MASK);

    k_select<<<N_IMG, 1024, 0, stream>>>(obj, boxreg, boxes, corn, area, rad, vmask, tscr);
    k_iou<<<N_IMG * PRE, 256, 0, stream>>>(boxes, corn, area, rad, masks);
    k_nms_out<<<N_IMG, 1024, 0, stream>>>(masks, vmask, boxes, tscr, out);
}